// Round 16
// baseline (542.253 us; speedup 1.0000x reference)
//
#include <hip/hip_runtime.h>
#include <hip/hip_cooperative_groups.h>
#include <hip/hip_bf16.h>
#include <math.h>

namespace cg = cooperative_groups;

// Problem constants (fixed by the reference)
#define NT    10000      // total nodes (BL*N)
#define NE    120000     // edges
#define MP    10240      // NT padded to 80*128 (GEMM row tiles)

using h8    = __attribute__((ext_vector_type(8))) _Float16;
using h4    = __attribute__((ext_vector_type(4))) _Float16;
using f32x4 = __attribute__((ext_vector_type(4))) float;

struct Args {
    const float* x;
    const int*   src;
    const int*   dst;
    const float* ew;
    const float* W[6];        // Wl0,Wr0,Wl1,Wr1,Wl2,Wr2 (fp32 [K][N])
    const float* bl[3];
    const float* br[3];
    const float* We[3];
    const float* att[3];
    const float* bias[3];
    _Float16* wt[6];          // transposed fp16 [N][K]
    _Float16* xf;             // x as fp16
    _Float16* xl;  _Float16* xr;
    _Float16* af;             // activations fp16
    float* out;
    int* rowptr; int* cntcur; int* csr_src; float* csr_w;
};

// ---------------------------------------------------------------------------
// Phase functions (shared by the cooperative head kernel and the fallback
// dispatches). All grid-stride on (b0, nb).
// ---------------------------------------------------------------------------
__device__ __forceinline__ void prep_phase(const Args& a, int b0, int nb,
                                           float* sf) {
    const int mat_cum[7] = {0, 32, 64, 320, 576, 704, 832};
    const int mat_K[6]   = {64, 64, 512, 512, 512, 512};
    const int mat_N[6]   = {512, 512, 512, 512, 256, 256};
    int tid = threadIdx.x;
    int tx = tid & 31, ty = tid >> 5;
    for (int w = b0; w < 3411; w += nb) {
        if (w < 79) {
            int i = w * 256 + tid;
            if (i < 2 * NT) a.cntcur[i] = 0;
        } else if (w < 911) {
            int t = w - 79;
            int mm = 0;
            #pragma unroll
            for (int q = 1; q < 6; ++q) if (t >= mat_cum[q]) mm = q;
            int tt = t - mat_cum[mm];
            int K = mat_K[mm], N = mat_N[mm];
            int tiles_k = K >> 5;
            int tk = tt % tiles_k, tn = tt / tiles_k;
            const float* W = a.W[mm];
            _Float16* T = a.wt[mm];
            int bk = tk * 32, bn = tn * 32;
            __syncthreads();
            #pragma unroll
            for (int i = 0; i < 4; ++i)
                sf[(ty * 4 + i) * 33 + tx] =
                    W[(size_t)(bk + ty * 4 + i) * N + bn + tx];
            __syncthreads();
            #pragma unroll
            for (int i = 0; i < 4; ++i) {
                int nn = ty * 4 + i;
                T[(size_t)(bn + nn) * K + bk + tx] = (_Float16)sf[tx * 33 + nn];
            }
        } else {
            int i = (w - 911) * 256 + tid;   // exactly covers NT*64
            a.xf[i] = (_Float16)a.x[i];
        }
    }
}

__device__ __forceinline__ void hist_phase(const Args& a, int b0, int nb) {
    for (int e = b0 * 256 + (int)threadIdx.x; e < NE; e += nb * 256)
        atomicAdd(&a.cntcur[a.dst[e]], 1);
}

__device__ __forceinline__ void scan_phase(const Args& a, int* si) {
    int tid = threadIdx.x;
    const int PER = 40;   // 256*40 = 10240 >= NT+1
    int base = tid * PER;
    int s = 0;
    for (int i = 0; i < PER; ++i) {
        int idx = base + i;
        if (idx < NT) s += a.cntcur[idx];
    }
    si[tid] = s;
    __syncthreads();
    for (int off = 1; off < 256; off <<= 1) {
        int v = (tid >= off) ? si[tid - off] : 0;
        __syncthreads();
        si[tid] += v;
        __syncthreads();
    }
    int run = (tid == 0) ? 0 : si[tid - 1];
    for (int i = 0; i < PER; ++i) {
        int idx = base + i;
        if (idx < NT) { a.rowptr[idx] = run; run += a.cntcur[idx]; }
        else if (idx == NT) a.rowptr[idx] = run;
    }
}

__device__ __forceinline__ void scatter_phase(const Args& a, int b0, int nb) {
    int* cursor = a.cntcur + NT;
    for (int e = b0 * 256 + (int)threadIdx.x; e < NE; e += nb * 256) {
        int d = a.dst[e];
        int pos = atomicAdd(&cursor[d], 1);
        int idx = a.rowptr[d] + pos;
        a.csr_src[idx] = a.src[e];
        a.csr_w[idx]  = a.ew[e];
    }
}

// ---------------------------------------------------------------------------
// Pure-fp16 MFMA GEMM jobs (r14 structure): Wl & Wr fused by job id.
// Block tile 128x128, BK=64, 4 waves, wave tile 64x64, LDS 32 KB.
// Fragment-contiguous glds staging (conflict-free ds_read_b128),
// XCD-slab job swizzle. njobs = 80 * 2 * (N/128).
// ---------------------------------------------------------------------------
__device__ __forceinline__ void gemm_jobs(
    const _Float16* __restrict__ A,
    const _Float16* __restrict__ WlT, const _Float16* __restrict__ WrT,
    const float* __restrict__ biasl, const float* __restrict__ biasr,
    _Float16* __restrict__ outl, _Float16* __restrict__ outr,
    int M, int N, int K, int njobs, int job0, int jstep, _Float16* sm)
{
    _Float16* sA = sm;
    _Float16* sB = sm + 8192;

    int tid = threadIdx.x;
    int wave = tid >> 6, lane = tid & 63;
    int lr15 = lane & 15;
    int lk8  = (lane >> 4) * 8;
    int fq = lane >> 4;
    int fc = lane & 15;
    int wm = (wave & 1) << 6;
    int wn = (wave >> 1) << 6;

    for (int job = job0; job < njobs; job += jstep) {
        int xcd = job & 7;
        int kk  = job >> 3;
        int r   = kk % 10;
        int byy = kk / 10;
        int bm  = (xcd * 10 + r) * 128;

        int nby = N >> 7;
        bool isR = byy >= nby;
        int bnn = (isR ? byy - nby : byy) << 7;
        const _Float16* Bh = isR ? WrT : WlT;
        const float* bias  = isR ? biasr : biasl;
        _Float16* out      = isR ? outr : outl;

        f32x4 acc[4][4] = {};

        for (int k0 = 0; k0 < K; k0 += 64) {
            __syncthreads();
            #pragma unroll
            for (int q = 0; q < 8; ++q) {
                int p = wave * 8 + q;         // 0..31
                int bufi = p >> 4;            // 0:A 1:B
                int c = p & 15;               // chunk: sub=c>>3, rowgrp=c&7
                int sub = c >> 3, rg = c & 7;
                const _Float16* g = (bufi == 0) ? A : Bh;
                int rowbase = (bufi == 0) ? bm : bnn;
                _Float16* sb = sm + bufi * 8192 + c * 512;
                const _Float16* gp = g + (size_t)(rowbase + rg * 16 + lr15) * K
                                       + k0 + sub * 32 + lk8;
                __builtin_amdgcn_global_load_lds(
                    (const __attribute__((address_space(1))) void*)gp,
                    (__attribute__((address_space(3))) void*)sb,
                    16, 0, 0);
            }
            __syncthreads();

            #pragma unroll
            for (int sub = 0; sub < 2; ++sub) {
                h8 af[4];
                #pragma unroll
                for (int i = 0; i < 4; ++i) {
                    int c = sub * 8 + (wave & 1) * 4 + i;
                    af[i] = *(const h8*)(sA + c * 512 + lane * 8);
                }
                #pragma unroll
                for (int j = 0; j < 4; ++j) {
                    int c = sub * 8 + (wave >> 1) * 4 + j;
                    h8 bf = *(const h8*)(sB + c * 512 + lane * 8);
                    #pragma unroll
                    for (int i = 0; i < 4; ++i)
                        acc[i][j] = __builtin_amdgcn_mfma_f32_16x16x32_f16(af[i], bf, acc[i][j], 0, 0, 0);
                }
            }
        }

        __syncthreads();   // LDS reuse safe before next job
        #pragma unroll
        for (int j = 0; j < 4; ++j) {
            int col = bnn + wn + j * 16 + fc;
            float bv = bias[col];
            #pragma unroll
            for (int i = 0; i < 4; ++i) {
                int row0 = bm + wm + i * 16 + fq * 4;
                #pragma unroll
                for (int reg = 0; reg < 4; ++reg) {
                    int row = row0 + reg;
                    if (row < M)
                        out[(size_t)row * N + col] = (_Float16)(acc[i][j][reg] + bv);
                }
            }
        }
    }
}

// ---------------------------------------------------------------------------
// Cooperative HEAD kernel: prep + hist + (scan || gemmL0) + (scatter ||
// gemmL0 tail). All phases <= 640-block parallelism, so coop residency
// costs nothing (unlike the r12 full fusion, which strangled the edges).
// ---------------------------------------------------------------------------
__global__ __launch_bounds__(256, 4) void head_k(Args a) {
    cg::grid_group grid = cg::this_grid();
    __shared__ __align__(16) _Float16 sm[2 * 8192];   // 32 KB
    int b = blockIdx.x, G = gridDim.x;

    prep_phase(a, b, G, (float*)sm);
    grid.sync();

    hist_phase(a, b, G);
    grid.sync();

    // scan (block 0) || GEMM L0 jobs 0..638
    if (b == 0) scan_phase(a, (int*)sm);
    else gemm_jobs(a.xf, a.wt[0], a.wt[1], a.bl[0], a.br[0],
                   a.xl, a.xr, NT, 512, 64, 639, b - 1, G - 1, sm);
    grid.sync();

    // GEMM L0 job 639 (block 0) || scatter
    if (b == 0) gemm_jobs(a.xf, a.wt[0], a.wt[1], a.bl[0], a.br[0],
                          a.xl, a.xr, NT, 512, 64, 640, 639, 1, sm);
    else scatter_phase(a, b - 1, G - 1);
}

// ---------------------------------------------------------------------------
// Fallback wrappers (if cooperative launch is rejected)
// ---------------------------------------------------------------------------
__global__ void prep_k(Args a) {
    __shared__ float sf[32 * 33];
    prep_phase(a, blockIdx.x, gridDim.x, sf);
}
__global__ void hist_k(Args a) { hist_phase(a, blockIdx.x, gridDim.x); }
__global__ void scan_k(Args a) {
    __shared__ int si[256];
    scan_phase(a, si);
}
__global__ void scatter_k(Args a) { scatter_phase(a, blockIdx.x, gridDim.x); }

__global__ __launch_bounds__(256, 4) void gemm_k(
    const _Float16* A, const _Float16* WlT, const _Float16* WrT,
    const float* bl, const float* br,
    _Float16* ol, _Float16* orr, int M, int N, int K, int njobs) {
    __shared__ __align__(16) _Float16 sm[2 * 8192];
    gemm_jobs(A, WlT, WrT, bl, br, ol, orr, M, N, K, njobs,
              blockIdx.x, gridDim.x, sm);
}

// ---------------------------------------------------------------------------
// Fused edge attention (r15): all heads in one wave per node, online
// softmax, chunked index broadcast + depth-3 row-gather pipeline.
// ---------------------------------------------------------------------------
template<int C, int H, bool DO_ELU, bool FP16OUT>
__global__ __launch_bounds__(256) void edge_k(
    const _Float16* __restrict__ xl, const _Float16* __restrict__ xr,
    const int* __restrict__ rowptr, const int* __restrict__ csr_src,
    const float* __restrict__ csr_w,
    const float* __restrict__ We, const float* __restrict__ att,
    const float* __restrict__ bias,
    float* __restrict__ outf, _Float16* __restrict__ outh)
{
    constexpr int CHT = C * H;        // flat channels per node
    constexpr int VPT = CHT / 64;     // channels per lane
    constexpr int G   = 64 / H;       // lanes per head group

    int node = (blockIdx.x * 256 + threadIdx.x) >> 6;
    int lane = threadIdx.x & 63;
    if (node >= NT) return;
    int c0 = lane * VPT;
    size_t nbase = (size_t)node * CHT + c0;

    float xr_reg[VPT], we_reg[VPT], att_reg[VPT], bias_reg[VPT];
    {
        _Float16 t[VPT];
        if (VPT == 8) *(h8*)t = *(const h8*)(xr + nbase);
        else          *(h4*)t = *(const h4*)(xr + nbase);
        #pragma unroll
        for (int v = 0; v < VPT; ++v) xr_reg[v] = (float)t[v];
    }
    #pragma unroll
    for (int v = 0; v < VPT; v += 4) {
        *(float4*)(we_reg + v)   = *(const float4*)(We + c0 + v);
        *(float4*)(att_reg + v)  = *(const float4*)(att + c0 + v);
        *(float4*)(bias_reg + v) = *(const float4*)(bias + c0 + v);
    }

    int rs = rowptr[node];
    int re = rowptr[node + 1];

    float m = -INFINITY, ssum = 0.f;
    float av[VPT];
    #pragma unroll
    for (int v = 0; v < VPT; ++v) av[v] = 0.f;

    for (int base = rs; base < re; base += 64) {
        int cn = re - base;
        if (cn > 64) cn = 64;
        int le = base + lane;
        int cl = (le < re) ? le : (re - 1);
        int   sidx = csr_src[cl];
        float swt  = csr_w[cl];

        _Float16 r0[VPT], r1[VPT], r2[VPT];
        auto ld = [&](int j, _Float16* dst) {
            int s = __shfl(sidx, j, 64);
            const _Float16* p = xl + (size_t)s * CHT + c0;
            if (VPT == 8) *(h8*)dst = *(const h8*)p;
            else          *(h4*)dst = *(const h4*)p;
        };
        auto step = [&](const _Float16* rc, int j) {
            float w = __shfl(swt, j, 64);
            float xlv[VPT];
            #pragma unroll
            for (int v = 0; v < VPT; ++v) xlv[v] = (float)rc[v];
            float part = 0.f;
            #pragma unroll
            for (int v = 0; v < VPT; ++v) {
                float t = xlv[v] + xr_reg[v] + w * we_reg[v];
                t = fmaxf(t, 0.f) + 0.2f * fminf(t, 0.f);
                part += t * att_reg[v];
            }
            #pragma unroll
            for (int off = G / 2; off > 0; off >>= 1)
                part += __shfl_xor(part, off, 64);
            float newm = fmaxf(m, part);
            float fac = __expf(m - newm);
            float p = __expf(part - newm);
            ssum = ssum * fac + p;
            #pragma unroll
            for (int v = 0; v < VPT; ++v) av[v] = av[v] * fac + p * xlv[v];
            m = newm;
        };

        ld(0, r0);
        if (cn > 1) ld(1, r1);
        if (cn > 2) ld(2, r2);

        int j = 0;
        while (j < cn) {
            step(r0, j);
            if (j + 3 < cn) ld(j + 3, r0);
            if (++j >= cn) break;
            step(r1, j);
            if (j + 3 < cn) ld(j + 3, r1);
            if (++j >= cn) break;
            step(r2, j);
            if (j + 3 < cn) ld(j + 3, r2);
            ++j;
        }
    }

    float inv = 1.f / (ssum + 1e-16f);
    #pragma unroll
    for (int v = 0; v < VPT; ++v) {
        float o = av[v] * inv + bias_reg[v];
        if (DO_ELU) o = (o > 0.f) ? o : (__expf(o) - 1.f);
        if (FP16OUT) outh[nbase + v] = (_Float16)o;
        else         outf[nbase + v] = o;
    }
}

// ---------------------------------------------------------------------------
extern "C" void kernel_launch(void* const* d_in, const int* in_sizes, int n_in,
                              void* d_out, int out_size, void* d_ws, size_t ws_size,
                              hipStream_t stream) {
    Args a;
    a.x   = (const float*)d_in[0];
    const int* ei = (const int*)d_in[1];
    a.src = ei;
    a.dst = ei + NE;
    a.ew  = (const float*)d_in[2];
    for (int l = 0; l < 3; ++l) {
        int base = 3 + 7 * l;
        a.W[2 * l]     = (const float*)d_in[base + 0];   // Wl
        a.bl[l]        = (const float*)d_in[base + 1];
        a.W[2 * l + 1] = (const float*)d_in[base + 2];   // Wr
        a.br[l]        = (const float*)d_in[base + 3];
        a.We[l]        = (const float*)d_in[base + 4];
        a.att[l]       = (const float*)d_in[base + 5];
        a.bias[l]      = (const float*)d_in[base + 6];
    }

    size_t off = 0;
    auto alloc = [&](size_t bytes) -> void* {
        void* p = (char*)d_ws + off;
        off += (bytes + 255) & ~(size_t)255;
        return p;
    };
    a.xl   = (_Float16*)alloc((size_t)MP * 512 * 2);
    a.xr   = (_Float16*)alloc((size_t)MP * 512 * 2);
    a.af   = (_Float16*)alloc((size_t)MP * 512 * 2);
    a.xf   = (_Float16*)alloc((size_t)MP * 64 * 2);
    const int KD[3] = {64, 512, 512};
    const int ND[3] = {512, 512, 256};
    for (int l = 0; l < 3; ++l) {
        a.wt[2 * l]     = (_Float16*)alloc((size_t)KD[l] * ND[l] * 2);
        a.wt[2 * l + 1] = (_Float16*)alloc((size_t)KD[l] * ND[l] * 2);
    }
    a.rowptr  = (int*)alloc((size_t)(NT + 1) * 4);
    a.cntcur  = (int*)alloc((size_t)2 * NT * 4);
    a.csr_src = (int*)alloc((size_t)NE * 4);
    a.csr_w   = (float*)alloc((size_t)NE * 4);
    a.out     = (float*)d_out;

    // ---- cooperative head (prep + CSR + GEMM L0), checked, with fallback
    void* params[] = { (void*)&a };
    bool ok = false;
    const int grids[2] = {640, 512};
    for (int gi = 0; gi < 2 && !ok; ++gi) {
        hipError_t err = hipLaunchCooperativeKernel(
            (const void*)head_k, dim3(grids[gi]), dim3(256), params, 0, stream);
        if (err == hipSuccess) ok = true;
        else (void)hipGetLastError();   // clear sticky error
    }
    if (!ok) {
        prep_k<<<640, 256, 0, stream>>>(a);
        hist_k<<<469, 256, 0, stream>>>(a);
        scan_k<<<1, 256, 0, stream>>>(a);
        scatter_k<<<469, 256, 0, stream>>>(a);
        gemm_k<<<640, 256, 0, stream>>>(a.xf, a.wt[0], a.wt[1],
                                        a.bl[0], a.br[0], a.xl, a.xr,
                                        NT, 512, 64, 640);
    }

    // ---- Layer 0 edge
    edge_k<128, 4, true, true><<<2500, 256, 0, stream>>>(
        a.xl, a.xr, a.rowptr, a.csr_src, a.csr_w,
        a.We[0], a.att[0], a.bias[0], nullptr, a.af);

    // ---- Layer 1: K=512, N=512/side
    gemm_k<<<640, 256, 0, stream>>>(a.af, a.wt[2], a.wt[3],
                                    a.bl[1], a.br[1], a.xl, a.xr,
                                    NT, 512, 512, 640);
    edge_k<128, 4, true, true><<<2500, 256, 0, stream>>>(
        a.xl, a.xr, a.rowptr, a.csr_src, a.csr_w,
        a.We[1], a.att[1], a.bias[1], nullptr, a.af);

    // ---- Layer 2: K=512, N=256/side
    gemm_k<<<320, 256, 0, stream>>>(a.af, a.wt[4], a.wt[5],
                                    a.bl[2], a.br[2], a.xl, a.xr,
                                    NT, 256, 512, 320);
    edge_k<256, 1, false, false><<<2500, 256, 0, stream>>>(
        a.xl, a.xr, a.rowptr, a.csr_src, a.csr_w,
        a.We[2], a.att[2], a.bias[2], a.out, nullptr);
}

// Round 17
// 285.830 us; speedup vs baseline: 1.8971x; 1.8971x over previous
//
#include <hip/hip_runtime.h>
#include <hip/hip_bf16.h>
#include <math.h>

// Problem constants (fixed by the reference)
#define NT    10000      // total nodes (BL*N)
#define NE    120000     // edges
#define MP    10240      // NT padded to 80*128 (GEMM row tiles)

using h8    = __attribute__((ext_vector_type(8))) _Float16;
using h4    = __attribute__((ext_vector_type(4))) _Float16;
using f32x4 = __attribute__((ext_vector_type(4))) float;

struct Args {
    const float* x;
    const int*   src;
    const int*   dst;
    const float* ew;
    const float* W[6];        // Wl0,Wr0,Wl1,Wr1,Wl2,Wr2 (fp32 [K][N])
    const float* bl[3];
    const float* br[3];
    const float* We[3];
    const float* att[3];
    const float* bias[3];
    _Float16* wt[6];          // transposed fp16 [N][K]
    _Float16* xf;             // x as fp16
    _Float16* xl;  _Float16* xr;
    _Float16* af;             // activations fp16
    float* out;
    int* rowptr; int* cntcur; int* csr_src; float* csr_w;
};

// ---------------------------------------------------------------------------
// Pure-fp16 MFMA GEMM jobs (r14 structure, proven): Wl & Wr fused by job id.
// Block tile 128x128, BK=64, 4 waves, wave tile 64x64, LDS 32 KB.
// Fragment-contiguous glds staging (conflict-free ds_read_b128),
// XCD-slab job swizzle. njobs = 80 * 2 * (N/128).
// ---------------------------------------------------------------------------
__device__ __forceinline__ void gemm_jobs(
    const _Float16* __restrict__ A,
    const _Float16* __restrict__ WlT, const _Float16* __restrict__ WrT,
    const float* __restrict__ biasl, const float* __restrict__ biasr,
    _Float16* __restrict__ outl, _Float16* __restrict__ outr,
    int M, int N, int K, int njobs, int job0, int jstep, _Float16* sm)
{
    _Float16* sA = sm;
    _Float16* sB = sm + 8192;

    int tid = threadIdx.x;
    int wave = tid >> 6, lane = tid & 63;
    int lr15 = lane & 15;
    int lk8  = (lane >> 4) * 8;
    int fq = lane >> 4;
    int fc = lane & 15;
    int wm = (wave & 1) << 6;
    int wn = (wave >> 1) << 6;

    for (int job = job0; job < njobs; job += jstep) {
        int xcd = job & 7;
        int kk  = job >> 3;
        int r   = kk % 10;
        int byy = kk / 10;
        int bm  = (xcd * 10 + r) * 128;

        int nby = N >> 7;
        bool isR = byy >= nby;
        int bnn = (isR ? byy - nby : byy) << 7;
        const _Float16* Bh = isR ? WrT : WlT;
        const float* bias  = isR ? biasr : biasl;
        _Float16* out      = isR ? outr : outl;

        f32x4 acc[4][4] = {};

        for (int k0 = 0; k0 < K; k0 += 64) {
            __syncthreads();
            #pragma unroll
            for (int q = 0; q < 8; ++q) {
                int p = wave * 8 + q;         // 0..31
                int bufi = p >> 4;            // 0:A 1:B
                int c = p & 15;               // chunk: sub=c>>3, rowgrp=c&7
                int sub = c >> 3, rg = c & 7;
                const _Float16* g = (bufi == 0) ? A : Bh;
                int rowbase = (bufi == 0) ? bm : bnn;
                _Float16* sb = sm + bufi * 8192 + c * 512;
                const _Float16* gp = g + (size_t)(rowbase + rg * 16 + lr15) * K
                                       + k0 + sub * 32 + lk8;
                __builtin_amdgcn_global_load_lds(
                    (const __attribute__((address_space(1))) void*)gp,
                    (__attribute__((address_space(3))) void*)sb,
                    16, 0, 0);
            }
            __syncthreads();

            #pragma unroll
            for (int sub = 0; sub < 2; ++sub) {
                h8 af[4];
                #pragma unroll
                for (int i = 0; i < 4; ++i) {
                    int c = sub * 8 + (wave & 1) * 4 + i;
                    af[i] = *(const h8*)(sA + c * 512 + lane * 8);
                }
                #pragma unroll
                for (int j = 0; j < 4; ++j) {
                    int c = sub * 8 + (wave >> 1) * 4 + j;
                    h8 bf = *(const h8*)(sB + c * 512 + lane * 8);
                    #pragma unroll
                    for (int i = 0; i < 4; ++i)
                        acc[i][j] = __builtin_amdgcn_mfma_f32_16x16x32_f16(af[i], bf, acc[i][j], 0, 0, 0);
                }
            }
        }

        __syncthreads();   // LDS reuse safe before next job
        #pragma unroll
        for (int j = 0; j < 4; ++j) {
            int col = bnn + wn + j * 16 + fc;
            float bv = bias[col];
            #pragma unroll
            for (int i = 0; i < 4; ++i) {
                int row0 = bm + wm + i * 16 + fq * 4;
                #pragma unroll
                for (int reg = 0; reg < 4; ++reg) {
                    int row = row0 + reg;
                    if (row < M)
                        out[(size_t)row * N + col] = (_Float16)(acc[i][j][reg] + bv);
                }
            }
        }
    }
}

// ---------------------------------------------------------------------------
// prep + hist FUSED (independent once cnt/cursor zeroing moved to
// hipMemsetAsync): weight transpose (fp16) + x fp16 convert, then histogram.
// prep work ids: [0,832) weight tiles | [832,3332) x convert
// ---------------------------------------------------------------------------
__global__ void preph_k(Args a) {
    __shared__ float sf[32 * 33];
    const int mat_cum[7] = {0, 32, 64, 320, 576, 704, 832};
    const int mat_K[6]   = {64, 64, 512, 512, 512, 512};
    const int mat_N[6]   = {512, 512, 512, 512, 256, 256};
    int tid = threadIdx.x;
    int tx = tid & 31, ty = tid >> 5;
    for (int w = blockIdx.x; w < 3332; w += gridDim.x) {
        if (w < 832) {
            int t = w;
            int mm = 0;
            #pragma unroll
            for (int q = 1; q < 6; ++q) if (t >= mat_cum[q]) mm = q;
            int tt = t - mat_cum[mm];
            int K = mat_K[mm], N = mat_N[mm];
            int tiles_k = K >> 5;
            int tk = tt % tiles_k, tn = tt / tiles_k;
            const float* W = a.W[mm];
            _Float16* T = a.wt[mm];
            int bk = tk * 32, bn = tn * 32;
            __syncthreads();
            #pragma unroll
            for (int i = 0; i < 4; ++i)
                sf[(ty * 4 + i) * 33 + tx] =
                    W[(size_t)(bk + ty * 4 + i) * N + bn + tx];
            __syncthreads();
            #pragma unroll
            for (int i = 0; i < 4; ++i) {
                int nn = ty * 4 + i;
                T[(size_t)(bn + nn) * K + bk + tx] = (_Float16)sf[tx * 33 + nn];
            }
        } else {
            int i = (w - 832) * 256 + tid;   // exactly covers NT*64
            a.xf[i] = (_Float16)a.x[i];
        }
    }
    // histogram (cnt zeroed by the preceding memset)
    for (int e = blockIdx.x * 256 + tid; e < NE; e += gridDim.x * 256)
        atomicAdd(&a.cntcur[a.dst[e]], 1);
}

// ---------------------------------------------------------------------------
// scan: one 1024-thread block, exclusive prefix over cnt -> rowptr
// ---------------------------------------------------------------------------
__global__ __launch_bounds__(1024) void scan_k(Args a) {
    __shared__ int si[1024];
    int tid = threadIdx.x;
    const int PER = 10;   // 1024*10 = 10240 >= NT+1
    int base = tid * PER;
    int s = 0;
    for (int i = 0; i < PER; ++i) {
        int idx = base + i;
        if (idx < NT) s += a.cntcur[idx];
    }
    si[tid] = s;
    __syncthreads();
    for (int off = 1; off < 1024; off <<= 1) {
        int v = (tid >= off) ? si[tid - off] : 0;
        __syncthreads();
        si[tid] += v;
        __syncthreads();
    }
    int run = (tid == 0) ? 0 : si[tid - 1];
    for (int i = 0; i < PER; ++i) {
        int idx = base + i;
        if (idx < NT) { a.rowptr[idx] = run; run += a.cntcur[idx]; }
        else if (idx == NT) a.rowptr[idx] = run;
    }
}

// ---------------------------------------------------------------------------
// scatter + GEMM L0 FUSED: both only need scan/prep outputs. Blocks [0,160)
// scatter edges into CSR; blocks [160,800) run the 640 GEMM-L0 jobs.
// Scatter (~6 us) hides entirely under GEMM L0 (~10 us).
// ---------------------------------------------------------------------------
__global__ __launch_bounds__(256, 4) void scatgemm_k(Args a) {
    __shared__ __align__(16) _Float16 sm[2 * 8192];   // 32 KB
    int b = blockIdx.x;
    if (b < 160) {
        int* cursor = a.cntcur + NT;
        for (int e = b * 256 + (int)threadIdx.x; e < NE; e += 160 * 256) {
            int d = a.dst[e];
            int pos = atomicAdd(&cursor[d], 1);
            int idx = a.rowptr[d] + pos;
            a.csr_src[idx] = a.src[e];
            a.csr_w[idx]  = a.ew[e];
        }
    } else {
        gemm_jobs(a.xf, a.wt[0], a.wt[1], a.bl[0], a.br[0],
                  a.xl, a.xr, NT, 512, 64, 640, b - 160, 640, sm);
    }
}

// ---------------------------------------------------------------------------
// standalone GEMM (layers 1, 2)
// ---------------------------------------------------------------------------
__global__ __launch_bounds__(256, 4) void gemm_k(
    const _Float16* A, const _Float16* WlT, const _Float16* WrT,
    const float* bl, const float* br,
    _Float16* ol, _Float16* orr, int M, int N, int K, int njobs) {
    __shared__ __align__(16) _Float16 sm[2 * 8192];
    gemm_jobs(A, WlT, WrT, bl, br, ol, orr, M, N, K, njobs,
              blockIdx.x, gridDim.x, sm);
}

// ---------------------------------------------------------------------------
// Fused edge attention (r15, proven): all heads in one wave per node,
// online softmax, chunked index broadcast + depth-3 row-gather pipeline.
// ---------------------------------------------------------------------------
template<int C, int H, bool DO_ELU, bool FP16OUT>
__global__ __launch_bounds__(256) void edge_k(
    const _Float16* __restrict__ xl, const _Float16* __restrict__ xr,
    const int* __restrict__ rowptr, const int* __restrict__ csr_src,
    const float* __restrict__ csr_w,
    const float* __restrict__ We, const float* __restrict__ att,
    const float* __restrict__ bias,
    float* __restrict__ outf, _Float16* __restrict__ outh)
{
    constexpr int CHT = C * H;        // flat channels per node
    constexpr int VPT = CHT / 64;     // channels per lane
    constexpr int G   = 64 / H;       // lanes per head group

    int node = (blockIdx.x * 256 + threadIdx.x) >> 6;
    int lane = threadIdx.x & 63;
    if (node >= NT) return;
    int c0 = lane * VPT;
    size_t nbase = (size_t)node * CHT + c0;

    float xr_reg[VPT], we_reg[VPT], att_reg[VPT], bias_reg[VPT];
    {
        _Float16 t[VPT];
        if (VPT == 8) *(h8*)t = *(const h8*)(xr + nbase);
        else          *(h4*)t = *(const h4*)(xr + nbase);
        #pragma unroll
        for (int v = 0; v < VPT; ++v) xr_reg[v] = (float)t[v];
    }
    #pragma unroll
    for (int v = 0; v < VPT; v += 4) {
        *(float4*)(we_reg + v)   = *(const float4*)(We + c0 + v);
        *(float4*)(att_reg + v)  = *(const float4*)(att + c0 + v);
        *(float4*)(bias_reg + v) = *(const float4*)(bias + c0 + v);
    }

    int rs = rowptr[node];
    int re = rowptr[node + 1];

    float m = -INFINITY, ssum = 0.f;
    float av[VPT];
    #pragma unroll
    for (int v = 0; v < VPT; ++v) av[v] = 0.f;

    for (int base = rs; base < re; base += 64) {
        int cn = re - base;
        if (cn > 64) cn = 64;
        int le = base + lane;
        int cl = (le < re) ? le : (re - 1);
        int   sidx = csr_src[cl];
        float swt  = csr_w[cl];

        _Float16 r0[VPT], r1[VPT], r2[VPT];
        auto ld = [&](int j, _Float16* dst) {
            int s = __shfl(sidx, j, 64);
            const _Float16* p = xl + (size_t)s * CHT + c0;
            if (VPT == 8) *(h8*)dst = *(const h8*)p;
            else          *(h4*)dst = *(const h4*)p;
        };
        auto step = [&](const _Float16* rc, int j) {
            float w = __shfl(swt, j, 64);
            float xlv[VPT];
            #pragma unroll
            for (int v = 0; v < VPT; ++v) xlv[v] = (float)rc[v];
            float part = 0.f;
            #pragma unroll
            for (int v = 0; v < VPT; ++v) {
                float t = xlv[v] + xr_reg[v] + w * we_reg[v];
                t = fmaxf(t, 0.f) + 0.2f * fminf(t, 0.f);
                part += t * att_reg[v];
            }
            #pragma unroll
            for (int off = G / 2; off > 0; off >>= 1)
                part += __shfl_xor(part, off, 64);
            float newm = fmaxf(m, part);
            float fac = __expf(m - newm);
            float p = __expf(part - newm);
            ssum = ssum * fac + p;
            #pragma unroll
            for (int v = 0; v < VPT; ++v) av[v] = av[v] * fac + p * xlv[v];
            m = newm;
        };

        ld(0, r0);
        if (cn > 1) ld(1, r1);
        if (cn > 2) ld(2, r2);

        int j = 0;
        while (j < cn) {
            step(r0, j);
            if (j + 3 < cn) ld(j + 3, r0);
            if (++j >= cn) break;
            step(r1, j);
            if (j + 3 < cn) ld(j + 3, r1);
            if (++j >= cn) break;
            step(r2, j);
            if (j + 3 < cn) ld(j + 3, r2);
            ++j;
        }
    }

    float inv = 1.f / (ssum + 1e-16f);
    #pragma unroll
    for (int v = 0; v < VPT; ++v) {
        float o = av[v] * inv + bias_reg[v];
        if (DO_ELU) o = (o > 0.f) ? o : (__expf(o) - 1.f);
        if (FP16OUT) outh[nbase + v] = (_Float16)o;
        else         outf[nbase + v] = o;
    }
}

// ---------------------------------------------------------------------------
extern "C" void kernel_launch(void* const* d_in, const int* in_sizes, int n_in,
                              void* d_out, int out_size, void* d_ws, size_t ws_size,
                              hipStream_t stream) {
    Args a;
    a.x   = (const float*)d_in[0];
    const int* ei = (const int*)d_in[1];
    a.src = ei;
    a.dst = ei + NE;
    a.ew  = (const float*)d_in[2];
    for (int l = 0; l < 3; ++l) {
        int base = 3 + 7 * l;
        a.W[2 * l]     = (const float*)d_in[base + 0];   // Wl
        a.bl[l]        = (const float*)d_in[base + 1];
        a.W[2 * l + 1] = (const float*)d_in[base + 2];   // Wr
        a.br[l]        = (const float*)d_in[base + 3];
        a.We[l]        = (const float*)d_in[base + 4];
        a.att[l]       = (const float*)d_in[base + 5];
        a.bias[l]      = (const float*)d_in[base + 6];
    }

    size_t off = 0;
    auto alloc = [&](size_t bytes) -> void* {
        void* p = (char*)d_ws + off;
        off += (bytes + 255) & ~(size_t)255;
        return p;
    };
    a.xl   = (_Float16*)alloc((size_t)MP * 512 * 2);
    a.xr   = (_Float16*)alloc((size_t)MP * 512 * 2);
    a.af   = (_Float16*)alloc((size_t)MP * 512 * 2);
    a.xf   = (_Float16*)alloc((size_t)MP * 64 * 2);
    const int KD[3] = {64, 512, 512};
    const int ND[3] = {512, 512, 256};
    for (int l = 0; l < 3; ++l) {
        a.wt[2 * l]     = (_Float16*)alloc((size_t)KD[l] * ND[l] * 2);
        a.wt[2 * l + 1] = (_Float16*)alloc((size_t)KD[l] * ND[l] * 2);
    }
    a.rowptr  = (int*)alloc((size_t)(NT + 1) * 4);
    a.cntcur  = (int*)alloc((size_t)2 * NT * 4);
    a.csr_src = (int*)alloc((size_t)NE * 4);
    a.csr_w   = (float*)alloc((size_t)NE * 4);
    a.out     = (float*)d_out;

    hipMemsetAsync(a.cntcur, 0, (size_t)2 * NT * 4, stream);
    preph_k<<<640, 256, 0, stream>>>(a);
    scan_k<<<1, 1024, 0, stream>>>(a);
    scatgemm_k<<<800, 256, 0, stream>>>(a);   // scatter || GEMM L0

    // Layer 0 edge
    edge_k<128, 4, true, true><<<2500, 256, 0, stream>>>(
        a.xl, a.xr, a.rowptr, a.csr_src, a.csr_w,
        a.We[0], a.att[0], a.bias[0], nullptr, a.af);

    // Layer 1: K=512, N=512/side
    gemm_k<<<640, 256, 0, stream>>>(a.af, a.wt[2], a.wt[3],
                                    a.bl[1], a.br[1], a.xl, a.xr,
                                    NT, 512, 512, 640);
    edge_k<128, 4, true, true><<<2500, 256, 0, stream>>>(
        a.xl, a.xr, a.rowptr, a.csr_src, a.csr_w,
        a.We[1], a.att[1], a.bias[1], nullptr, a.af);

    // Layer 2: K=512, N=256/side
    gemm_k<<<320, 256, 0, stream>>>(a.af, a.wt[4], a.wt[5],
                                    a.bl[2], a.br[2], a.xl, a.xr,
                                    NT, 256, 512, 320);
    edge_k<256, 1, false, false><<<2500, 256, 0, stream>>>(
        a.xl, a.xr, a.rowptr, a.csr_src, a.csr_w,
        a.We[2], a.att[2], a.bias[2], a.out, nullptr);
}

// Round 18
// 285.143 us; speedup vs baseline: 1.9017x; 1.0024x over previous
//
#include <hip/hip_runtime.h>
#include <hip/hip_bf16.h>
#include <math.h>

// Problem constants (fixed by the reference)
#define NT    10000      // total nodes (BL*N)
#define NE    120000     // edges
#define MP    10240      // NT padded to 80*128 (GEMM row tiles)

using h8    = __attribute__((ext_vector_type(8))) _Float16;
using h4    = __attribute__((ext_vector_type(4))) _Float16;
using f32x4 = __attribute__((ext_vector_type(4))) float;

struct Args {
    const float* x;
    const int*   src;
    const int*   dst;
    const float* ew;
    const float* W[6];        // Wl0,Wr0,Wl1,Wr1,Wl2,Wr2 (fp32 [K][N])
    const float* bl[3];
    const float* br[3];
    const float* We[3];
    const float* att[3];
    const float* bias[3];
    _Float16* wt[6];          // transposed fp16 [N][K]
    _Float16* xf;             // x as fp16
    _Float16* xl;  _Float16* xr;
    _Float16* af;             // activations fp16
    float* out;
    int* rowptr; int* cntcur; int* csr_src; float* csr_w;
};

// ---------------------------------------------------------------------------
// Pure-fp16 MFMA GEMM jobs (r14 structure, proven): Wl & Wr fused by job id.
// Block tile 128x128, BK=64, 4 waves, wave tile 64x64, LDS 32 KB.
// Fragment-contiguous glds staging (conflict-free ds_read_b128),
// XCD-slab job swizzle. njobs = 80 * 2 * (N/128).
// r18: job-end barrier removed (loop-top barrier already orders LDS reuse).
// ---------------------------------------------------------------------------
__device__ __forceinline__ void gemm_jobs(
    const _Float16* __restrict__ A,
    const _Float16* __restrict__ WlT, const _Float16* __restrict__ WrT,
    const float* __restrict__ biasl, const float* __restrict__ biasr,
    _Float16* __restrict__ outl, _Float16* __restrict__ outr,
    int M, int N, int K, int njobs, int job0, int jstep, _Float16* sm)
{
    _Float16* sA = sm;
    _Float16* sB = sm + 8192;

    int tid = threadIdx.x;
    int wave = tid >> 6, lane = tid & 63;
    int lr15 = lane & 15;
    int lk8  = (lane >> 4) * 8;
    int fq = lane >> 4;
    int fc = lane & 15;
    int wm = (wave & 1) << 6;
    int wn = (wave >> 1) << 6;

    for (int job = job0; job < njobs; job += jstep) {
        int xcd = job & 7;
        int kk  = job >> 3;
        int r   = kk % 10;
        int byy = kk / 10;
        int bm  = (xcd * 10 + r) * 128;

        int nby = N >> 7;
        bool isR = byy >= nby;
        int bnn = (isR ? byy - nby : byy) << 7;
        const _Float16* Bh = isR ? WrT : WlT;
        const float* bias  = isR ? biasr : biasl;
        _Float16* out      = isR ? outr : outl;

        f32x4 acc[4][4] = {};

        for (int k0 = 0; k0 < K; k0 += 64) {
            __syncthreads();   // prior LDS reads (this job or previous) done
            #pragma unroll
            for (int q = 0; q < 8; ++q) {
                int p = wave * 8 + q;         // 0..31
                int bufi = p >> 4;            // 0:A 1:B
                int c = p & 15;               // chunk: sub=c>>3, rowgrp=c&7
                int sub = c >> 3, rg = c & 7;
                const _Float16* g = (bufi == 0) ? A : Bh;
                int rowbase = (bufi == 0) ? bm : bnn;
                _Float16* sb = sm + bufi * 8192 + c * 512;
                const _Float16* gp = g + (size_t)(rowbase + rg * 16 + lr15) * K
                                       + k0 + sub * 32 + lk8;
                __builtin_amdgcn_global_load_lds(
                    (const __attribute__((address_space(1))) void*)gp,
                    (__attribute__((address_space(3))) void*)sb,
                    16, 0, 0);
            }
            __syncthreads();   // staging visible

            #pragma unroll
            for (int sub = 0; sub < 2; ++sub) {
                h8 af[4];
                #pragma unroll
                for (int i = 0; i < 4; ++i) {
                    int c = sub * 8 + (wave & 1) * 4 + i;
                    af[i] = *(const h8*)(sA + c * 512 + lane * 8);
                }
                #pragma unroll
                for (int j = 0; j < 4; ++j) {
                    int c = sub * 8 + (wave >> 1) * 4 + j;
                    h8 bf = *(const h8*)(sB + c * 512 + lane * 8);
                    #pragma unroll
                    for (int i = 0; i < 4; ++i)
                        acc[i][j] = __builtin_amdgcn_mfma_f32_16x16x32_f16(af[i], bf, acc[i][j], 0, 0, 0);
                }
            }
        }

        // epilogue: regs only (no LDS) -> no barrier needed before next job
        #pragma unroll
        for (int j = 0; j < 4; ++j) {
            int col = bnn + wn + j * 16 + fc;
            float bv = bias[col];
            #pragma unroll
            for (int i = 0; i < 4; ++i) {
                int row0 = bm + wm + i * 16 + fq * 4;
                #pragma unroll
                for (int reg = 0; reg < 4; ++reg) {
                    int row = row0 + reg;
                    if (row < M)
                        out[(size_t)row * N + col] = (_Float16)(acc[i][j][reg] + bv);
                }
            }
        }
    }
}

// ---------------------------------------------------------------------------
// prep + hist FUSED (cnt/cursor zeroing via hipMemsetAsync): weight
// transpose (fp16) + x fp16 convert, then histogram.
// prep work ids: [0,832) weight tiles | [832,3332) x convert
// ---------------------------------------------------------------------------
__global__ void preph_k(Args a) {
    __shared__ float sf[32 * 33];
    const int mat_cum[7] = {0, 32, 64, 320, 576, 704, 832};
    const int mat_K[6]   = {64, 64, 512, 512, 512, 512};
    const int mat_N[6]   = {512, 512, 512, 512, 256, 256};
    int tid = threadIdx.x;
    int tx = tid & 31, ty = tid >> 5;
    for (int w = blockIdx.x; w < 3332; w += gridDim.x) {
        if (w < 832) {
            int t = w;
            int mm = 0;
            #pragma unroll
            for (int q = 1; q < 6; ++q) if (t >= mat_cum[q]) mm = q;
            int tt = t - mat_cum[mm];
            int K = mat_K[mm], N = mat_N[mm];
            int tiles_k = K >> 5;
            int tk = tt % tiles_k, tn = tt / tiles_k;
            const float* W = a.W[mm];
            _Float16* T = a.wt[mm];
            int bk = tk * 32, bn = tn * 32;
            __syncthreads();
            #pragma unroll
            for (int i = 0; i < 4; ++i)
                sf[(ty * 4 + i) * 33 + tx] =
                    W[(size_t)(bk + ty * 4 + i) * N + bn + tx];
            __syncthreads();
            #pragma unroll
            for (int i = 0; i < 4; ++i) {
                int nn = ty * 4 + i;
                T[(size_t)(bn + nn) * K + bk + tx] = (_Float16)sf[tx * 33 + nn];
            }
        } else {
            int i = (w - 832) * 256 + tid;   // exactly covers NT*64
            a.xf[i] = (_Float16)a.x[i];
        }
    }
    // histogram (cnt zeroed by the preceding memset)
    for (int e = blockIdx.x * 256 + tid; e < NE; e += gridDim.x * 256)
        atomicAdd(&a.cntcur[a.dst[e]], 1);
}

// ---------------------------------------------------------------------------
// scan: one 1024-thread block, exclusive prefix over cnt -> rowptr
// ---------------------------------------------------------------------------
__global__ __launch_bounds__(1024) void scan_k(Args a) {
    __shared__ int si[1024];
    int tid = threadIdx.x;
    const int PER = 10;   // 1024*10 = 10240 >= NT+1
    int base = tid * PER;
    int s = 0;
    for (int i = 0; i < PER; ++i) {
        int idx = base + i;
        if (idx < NT) s += a.cntcur[idx];
    }
    si[tid] = s;
    __syncthreads();
    for (int off = 1; off < 1024; off <<= 1) {
        int v = (tid >= off) ? si[tid - off] : 0;
        __syncthreads();
        si[tid] += v;
        __syncthreads();
    }
    int run = (tid == 0) ? 0 : si[tid - 1];
    for (int i = 0; i < PER; ++i) {
        int idx = base + i;
        if (idx < NT) { a.rowptr[idx] = run; run += a.cntcur[idx]; }
        else if (idx == NT) a.rowptr[idx] = run;
    }
}

// ---------------------------------------------------------------------------
// scatter + GEMM L0 FUSED: blocks [0,160) scatter edges into CSR;
// blocks [160,800) run the 640 GEMM-L0 jobs. Scatter hides under GEMM L0.
// ---------------------------------------------------------------------------
__global__ __launch_bounds__(256, 4) void scatgemm_k(Args a) {
    __shared__ __align__(16) _Float16 sm[2 * 8192];   // 32 KB
    int b = blockIdx.x;
    if (b < 160) {
        int* cursor = a.cntcur + NT;
        for (int e = b * 256 + (int)threadIdx.x; e < NE; e += 160 * 256) {
            int d = a.dst[e];
            int pos = atomicAdd(&cursor[d], 1);
            int idx = a.rowptr[d] + pos;
            a.csr_src[idx] = a.src[e];
            a.csr_w[idx]  = a.ew[e];
        }
    } else {
        gemm_jobs(a.xf, a.wt[0], a.wt[1], a.bl[0], a.br[0],
                  a.xl, a.xr, NT, 512, 64, 640, b - 160, 640, sm);
    }
}

// ---------------------------------------------------------------------------
// standalone GEMM (layers 1, 2)
// ---------------------------------------------------------------------------
__global__ __launch_bounds__(256, 4) void gemm_k(
    const _Float16* A, const _Float16* WlT, const _Float16* WrT,
    const float* bl, const float* br,
    _Float16* ol, _Float16* orr, int M, int N, int K, int njobs) {
    __shared__ __align__(16) _Float16 sm[2 * 8192];
    gemm_jobs(A, WlT, WrT, bl, br, ol, orr, M, N, K, njobs,
              blockIdx.x, gridDim.x, sm);
}

// ---------------------------------------------------------------------------
// Fused edge attention: all heads in one wave per node, online softmax,
// chunked index broadcast + depth-4 row-gather pipeline (r18: was depth-3).
// ---------------------------------------------------------------------------
template<int C, int H, bool DO_ELU, bool FP16OUT>
__global__ __launch_bounds__(256) void edge_k(
    const _Float16* __restrict__ xl, const _Float16* __restrict__ xr,
    const int* __restrict__ rowptr, const int* __restrict__ csr_src,
    const float* __restrict__ csr_w,
    const float* __restrict__ We, const float* __restrict__ att,
    const float* __restrict__ bias,
    float* __restrict__ outf, _Float16* __restrict__ outh)
{
    constexpr int CHT = C * H;        // flat channels per node
    constexpr int VPT = CHT / 64;     // channels per lane
    constexpr int G   = 64 / H;       // lanes per head group

    int node = (blockIdx.x * 256 + threadIdx.x) >> 6;
    int lane = threadIdx.x & 63;
    if (node >= NT) return;
    int c0 = lane * VPT;
    size_t nbase = (size_t)node * CHT + c0;

    float xr_reg[VPT], we_reg[VPT], att_reg[VPT], bias_reg[VPT];
    {
        _Float16 t[VPT];
        if (VPT == 8) *(h8*)t = *(const h8*)(xr + nbase);
        else          *(h4*)t = *(const h4*)(xr + nbase);
        #pragma unroll
        for (int v = 0; v < VPT; ++v) xr_reg[v] = (float)t[v];
    }
    #pragma unroll
    for (int v = 0; v < VPT; v += 4) {
        *(float4*)(we_reg + v)   = *(const float4*)(We + c0 + v);
        *(float4*)(att_reg + v)  = *(const float4*)(att + c0 + v);
        *(float4*)(bias_reg + v) = *(const float4*)(bias + c0 + v);
    }

    int rs = rowptr[node];
    int re = rowptr[node + 1];

    float m = -INFINITY, ssum = 0.f;
    float av[VPT];
    #pragma unroll
    for (int v = 0; v < VPT; ++v) av[v] = 0.f;

    for (int base = rs; base < re; base += 64) {
        int cn = re - base;
        if (cn > 64) cn = 64;
        int le = base + lane;
        int cl = (le < re) ? le : (re - 1);
        int   sidx = csr_src[cl];
        float swt  = csr_w[cl];

        _Float16 r0[VPT], r1[VPT], r2[VPT], r3[VPT];
        auto ld = [&](int j, _Float16* dst) {
            int s = __shfl(sidx, j, 64);
            const _Float16* p = xl + (size_t)s * CHT + c0;
            if (VPT == 8) *(h8*)dst = *(const h8*)p;
            else          *(h4*)dst = *(const h4*)p;
        };
        auto step = [&](const _Float16* rc, int j) {
            float w = __shfl(swt, j, 64);
            float xlv[VPT];
            #pragma unroll
            for (int v = 0; v < VPT; ++v) xlv[v] = (float)rc[v];
            float part = 0.f;
            #pragma unroll
            for (int v = 0; v < VPT; ++v) {
                float t = xlv[v] + xr_reg[v] + w * we_reg[v];
                t = fmaxf(t, 0.f) + 0.2f * fminf(t, 0.f);
                part += t * att_reg[v];
            }
            #pragma unroll
            for (int off = G / 2; off > 0; off >>= 1)
                part += __shfl_xor(part, off, 64);
            float newm = fmaxf(m, part);
            float fac = __expf(m - newm);
            float p = __expf(part - newm);
            ssum = ssum * fac + p;
            #pragma unroll
            for (int v = 0; v < VPT; ++v) av[v] = av[v] * fac + p * xlv[v];
            m = newm;
        };

        ld(0, r0);
        if (cn > 1) ld(1, r1);
        if (cn > 2) ld(2, r2);
        if (cn > 3) ld(3, r3);

        int j = 0;
        while (j < cn) {
            step(r0, j);
            if (j + 4 < cn) ld(j + 4, r0);
            if (++j >= cn) break;
            step(r1, j);
            if (j + 4 < cn) ld(j + 4, r1);
            if (++j >= cn) break;
            step(r2, j);
            if (j + 4 < cn) ld(j + 4, r2);
            if (++j >= cn) break;
            step(r3, j);
            if (j + 4 < cn) ld(j + 4, r3);
            ++j;
        }
    }

    float inv = 1.f / (ssum + 1e-16f);
    #pragma unroll
    for (int v = 0; v < VPT; ++v) {
        float o = av[v] * inv + bias_reg[v];
        if (DO_ELU) o = (o > 0.f) ? o : (__expf(o) - 1.f);
        if (FP16OUT) outh[nbase + v] = (_Float16)o;
        else         outf[nbase + v] = o;
    }
}

// ---------------------------------------------------------------------------
extern "C" void kernel_launch(void* const* d_in, const int* in_sizes, int n_in,
                              void* d_out, int out_size, void* d_ws, size_t ws_size,
                              hipStream_t stream) {
    Args a;
    a.x   = (const float*)d_in[0];
    const int* ei = (const int*)d_in[1];
    a.src = ei;
    a.dst = ei + NE;
    a.ew  = (const float*)d_in[2];
    for (int l = 0; l < 3; ++l) {
        int base = 3 + 7 * l;
        a.W[2 * l]     = (const float*)d_in[base + 0];   // Wl
        a.bl[l]        = (const float*)d_in[base + 1];
        a.W[2 * l + 1] = (const float*)d_in[base + 2];   // Wr
        a.br[l]        = (const float*)d_in[base + 3];
        a.We[l]        = (const float*)d_in[base + 4];
        a.att[l]       = (const float*)d_in[base + 5];
        a.bias[l]      = (const float*)d_in[base + 6];
    }

    size_t off = 0;
    auto alloc = [&](size_t bytes) -> void* {
        void* p = (char*)d_ws + off;
        off += (bytes + 255) & ~(size_t)255;
        return p;
    };
    a.xl   = (_Float16*)alloc((size_t)MP * 512 * 2);
    a.xr   = (_Float16*)alloc((size_t)MP * 512 * 2);
    a.af   = (_Float16*)alloc((size_t)MP * 512 * 2);
    a.xf   = (_Float16*)alloc((size_t)MP * 64 * 2);
    const int KD[3] = {64, 512, 512};
    const int ND[3] = {512, 512, 256};
    for (int l = 0; l < 3; ++l) {
        a.wt[2 * l]     = (_Float16*)alloc((size_t)KD[l] * ND[l] * 2);
        a.wt[2 * l + 1] = (_Float16*)alloc((size_t)KD[l] * ND[l] * 2);
    }
    a.rowptr  = (int*)alloc((size_t)(NT + 1) * 4);
    a.cntcur  = (int*)alloc((size_t)2 * NT * 4);
    a.csr_src = (int*)alloc((size_t)NE * 4);
    a.csr_w   = (float*)alloc((size_t)NE * 4);
    a.out     = (float*)d_out;

    hipMemsetAsync(a.cntcur, 0, (size_t)2 * NT * 4, stream);
    preph_k<<<640, 256, 0, stream>>>(a);
    scan_k<<<1, 1024, 0, stream>>>(a);
    scatgemm_k<<<800, 256, 0, stream>>>(a);   // scatter || GEMM L0

    // Layer 0 edge
    edge_k<128, 4, true, true><<<2500, 256, 0, stream>>>(
        a.xl, a.xr, a.rowptr, a.csr_src, a.csr_w,
        a.We[0], a.att[0], a.bias[0], nullptr, a.af);

    // Layer 1: K=512, N=512/side
    gemm_k<<<640, 256, 0, stream>>>(a.af, a.wt[2], a.wt[3],
                                    a.bl[1], a.br[1], a.xl, a.xr,
                                    NT, 512, 512, 640);
    edge_k<128, 4, true, true><<<2500, 256, 0, stream>>>(
        a.xl, a.xr, a.rowptr, a.csr_src, a.csr_w,
        a.We[1], a.att[1], a.bias[1], nullptr, a.af);

    // Layer 2: K=512, N=256/side
    gemm_k<<<320, 256, 0, stream>>>(a.af, a.wt[4], a.wt[5],
                                    a.bl[2], a.br[2], a.xl, a.xr,
                                    NT, 256, 512, 320);
    edge_k<256, 1, false, false><<<2500, 256, 0, stream>>>(
        a.xl, a.xr, a.rowptr, a.csr_src, a.csr_w,
        a.We[2], a.att[2], a.bias[2], a.out, nullptr);
}